// Round 4
// baseline (2146.882 us; speedup 1.0000x reference)
//
#include <hip/hip_runtime.h>
#include <math.h>

// Problem dims (fixed by reference)
#define SE_B 64
#define SE_C 256
#define SE_L 4096
#define SE_R 16

#define NBLK 2048    // 8 blocks/CU x 256 CUs -> exactly co-resident capacity
#define ROUNDS 8     // 16384 rows / 2048 blocks

// Clang native vector type (required by __builtin_nontemporal_store).
typedef float vf4 __attribute__((ext_vector_type(4)));

// ---------------------------------------------------------------------------
// Single persistent kernel. Each block handles one (b,c) row per round:
//   phase 1: row -> registers (16 floats/thread), block-reduce mean
//   barrier: per-batch arrival counter (release/acquire, agent scope);
//            all 2048 blocks are co-resident (__launch_bounds__(256,8):
//            VGPR<=64, LDS ~1.2KB -> 8 blocks/CU guaranteed), so the spin
//            cannot deadlock.
//   phase 2: tiny MLP gate from the batch's 256 means (LDS)
//   phase 3: scale the registers, non-temporal store (out must not thrash
//            caches; x is never re-read)
// x is read from HBM exactly ONCE; total traffic 256MB R + 256MB W.
// ---------------------------------------------------------------------------
__global__ __launch_bounds__(256, 8) void se_fused_kernel(
    const float* __restrict__ x, const float* __restrict__ w1,
    const float* __restrict__ b1, const float* __restrict__ w2,
    const float* __restrict__ b2, float* __restrict__ out,
    float* __restrict__ means, int* __restrict__ cnt) {
  const int bid = blockIdx.x;
  const int t = threadIdx.x;
  const int r = bid & 7;   // residue class (likely XCD under %8 round-robin)
  const int s = bid >> 3;  // channel 0..255

  __shared__ float m_lds[SE_C];
  __shared__ float y_lds[SE_R];
  __shared__ float red[4];

  for (int round = 0; round < ROUNDS; ++round) {
    const int b = round * 8 + r;              // batch
    const size_t row = (size_t)b * SE_C + s;  // global row id
    const vf4* __restrict__ xrow = reinterpret_cast<const vf4*>(x + row * SE_L);

    // ---- phase 1: load row into registers, reduce to mean ----
    vf4 d0 = xrow[t];
    vf4 d1 = xrow[t + 256];
    vf4 d2 = xrow[t + 512];
    vf4 d3 = xrow[t + 768];
    float sum = ((d0.x + d0.y) + (d0.z + d0.w)) + ((d1.x + d1.y) + (d1.z + d1.w)) +
                ((d2.x + d2.y) + (d2.z + d2.w)) + ((d3.x + d3.y) + (d3.z + d3.w));
#pragma unroll
    for (int off = 32; off > 0; off >>= 1) sum += __shfl_down(sum, off, 64);
    if ((t & 63) == 0) red[t >> 6] = sum;
    __syncthreads();

    // ---- per-batch barrier: publish mean, wait for all 256 channels ----
    if (t == 0) {
      float tot = (red[0] + red[1]) + (red[2] + red[3]);
      means[row] = tot * (1.0f / SE_L);
      __threadfence();  // make the mean visible before the arrival
      __hip_atomic_fetch_add(&cnt[b], 1, __ATOMIC_RELEASE,
                             __HIP_MEMORY_SCOPE_AGENT);
      int guard = 0;
      while (__hip_atomic_load(&cnt[b], __ATOMIC_ACQUIRE,
                               __HIP_MEMORY_SCOPE_AGENT) < SE_C) {
        __builtin_amdgcn_s_sleep(2);
        if (++guard > (1 << 20)) break;  // hang guard (~0.1s): fail loud, not hung
      }
    }
    __syncthreads();

    // ---- phase 2: gate MLP for this batch ----
    // agent-scope relaxed load: served from L2 (coherence point), never stale L1
    m_lds[t] = __hip_atomic_load(&means[(size_t)b * SE_C + t], __ATOMIC_RELAXED,
                                 __HIP_MEMORY_SCOPE_AGENT);
    __syncthreads();
    if (t < SE_R) {
      float acc = b1[t];
      const float* __restrict__ w1r = w1 + t * SE_C;
#pragma unroll 8
      for (int c = 0; c < SE_C; ++c) acc += m_lds[c] * w1r[c];
      y_lds[t] = fmaxf(acc, 0.0f);
    }
    __syncthreads();
    float g = b2[s];
#pragma unroll
    for (int k = 0; k < SE_R; ++k) g += y_lds[k] * w2[s * SE_R + k];
    g = 1.0f / (1.0f + expf(-g));

    // ---- phase 3: scale registers, streaming store ----
    vf4* __restrict__ orow = reinterpret_cast<vf4*>(out + row * SE_L);
    __builtin_nontemporal_store(d0 * g, &orow[t]);
    __builtin_nontemporal_store(d1 * g, &orow[t + 256]);
    __builtin_nontemporal_store(d2 * g, &orow[t + 512]);
    __builtin_nontemporal_store(d3 * g, &orow[t + 768]);
    __syncthreads();  // protect red[]/m_lds before next round reuses them
  }
}

extern "C" void kernel_launch(void* const* d_in, const int* in_sizes, int n_in,
                              void* d_out, int out_size, void* d_ws,
                              size_t ws_size, hipStream_t stream) {
  const float* x = (const float*)d_in[0];
  const float* w1 = (const float*)d_in[1];
  const float* b1 = (const float*)d_in[2];
  const float* w2 = (const float*)d_in[3];
  const float* b2 = (const float*)d_in[4];
  float* out = (float*)d_out;

  float* means = (float*)d_ws;                 // 16384 floats = 64 KB
  int* cnt = (int*)((char*)d_ws + 64 * 1024);  // 64 arrival counters

  // counters must be zero at the start of EVERY replay (captured in graph)
  hipMemsetAsync(cnt, 0, SE_B * sizeof(int), stream);

  se_fused_kernel<<<NBLK, 256, 0, stream>>>(x, w1, b1, w2, b2, out, means, cnt);
}

// Round 5
// 153.449 us; speedup vs baseline: 13.9908x; 13.9908x over previous
//
#include <hip/hip_runtime.h>
#include <math.h>

// Problem dims (fixed by reference)
#define SE_B 64
#define SE_C 256
#define SE_L 4096
#define SE_R 16

#define CHUNK_B 8                         // batches per chunk
#define NCHUNK (SE_B / CHUNK_B)           // 8 chunks
#define CHUNK_ROWS (CHUNK_B * SE_C)       // 2048 rows per chunk (32 MB)

// Clang native vector type (required by __builtin_nontemporal_store).
typedef float vf4 __attribute__((ext_vector_type(4)));

// ---------------------------------------------------------------------------
// Software-pipelined chunked SE block. Kernel instance k does:
//   role 0 (mean):  compute per-row means of chunk k      (reads x from HBM,
//                   allocating it into the 256 MB MALL)
//   role 1 (scale): gate + scale rows of chunk k-1        (x read is a MALL
//                   hit - it was fetched one kernel ago; out is nt-stored so
//                   it does not thrash the cache)
// The producer->consumer dependency (means -> gate) crosses a kernel
// boundary, which is a full agent-scope release/acquire - no atomics/spins.
// Gate MLP is recomputed inside every scale block (4096 MACs over 256
// threads - trivial) to avoid separate tiny gate launches.
// ---------------------------------------------------------------------------
__global__ __launch_bounds__(256) void se_fused(
    const float* __restrict__ x, const float* __restrict__ w1,
    const float* __restrict__ b1, const float* __restrict__ w2,
    const float* __restrict__ b2, float* __restrict__ out,
    float* __restrict__ means, int mean_base, int scale_base, int both) {
  const int t = threadIdx.x;
  int role, idx;
  if (both) {
    role = blockIdx.x & 1;   // interleave roles -> balanced read/write mix
    idx = blockIdx.x >> 1;
  } else {
    role = (mean_base >= 0) ? 0 : 1;
    idx = blockIdx.x;
  }

  __shared__ float m_lds[SE_C];
  __shared__ float yp[SE_R][SE_R + 1];
  __shared__ float y_lds[SE_R];
  __shared__ float red[4];

  if (role == 0) {
    // ---- mean of row (mean_base + idx) ----
    const int row = mean_base + idx;
    const vf4* __restrict__ xrow =
        reinterpret_cast<const vf4*>(x + (size_t)row * SE_L);
    float s = 0.0f;
#pragma unroll
    for (int i = 0; i < 4; ++i) {
      vf4 v = xrow[t + (i << 8)];  // regular load: allocate into MALL
      s += (v.x + v.y) + (v.z + v.w);
    }
#pragma unroll
    for (int off = 32; off > 0; off >>= 1) s += __shfl_down(s, off, 64);
    if ((t & 63) == 0) red[t >> 6] = s;
    __syncthreads();
    if (t == 0) {
      float tot = (red[0] + red[1]) + (red[2] + red[3]);
      means[row] = tot * (1.0f / SE_L);
    }
  } else {
    // ---- gate + scale of row (scale_base + idx) ----
    const int row = scale_base + idx;
    const int c = row & (SE_C - 1);

    // batch means -> LDS (written by the previous kernel; dispatch-boundary
    // coherence makes them visible)
    m_lds[t] = means[row - c + t];
    __syncthreads();

    // hidden layer y[16], parallel over 256 threads: group g (16 threads)
    // computes y[g]; thread j of the group covers channels j, j+16, ...
    const int g = t >> 4, j = t & 15;
    float part = 0.0f;
    const float* __restrict__ w1g = w1 + (g << 8);
#pragma unroll
    for (int k = 0; k < 16; ++k) {
      const int ch = j + (k << 4);
      part += m_lds[ch] * w1g[ch];
    }
    yp[g][j] = part;
    __syncthreads();
    if (t < SE_R) {
      float acc = b1[t];
#pragma unroll
      for (int k = 0; k < 16; ++k) acc += yp[t][k];
      y_lds[t] = fmaxf(acc, 0.0f);
    }
    __syncthreads();

    // this channel's gate (computed redundantly by all threads)
    float gg = b2[c];
    const float* __restrict__ w2c = w2 + (c << 4);
#pragma unroll
    for (int r = 0; r < SE_R; ++r) gg += y_lds[r] * w2c[r];
    gg = 1.0f / (1.0f + expf(-gg));

    // scale the row: x read should hit MALL; out store is non-temporal
    const vf4* __restrict__ xrow =
        reinterpret_cast<const vf4*>(x + (size_t)row * SE_L);
    vf4* __restrict__ orow = reinterpret_cast<vf4*>(out + (size_t)row * SE_L);
#pragma unroll
    for (int i = 0; i < 4; ++i) {
      vf4 v = xrow[t + (i << 8)];
      __builtin_nontemporal_store(v * gg, &orow[t + (i << 8)]);
    }
  }
}

extern "C" void kernel_launch(void* const* d_in, const int* in_sizes, int n_in,
                              void* d_out, int out_size, void* d_ws,
                              size_t ws_size, hipStream_t stream) {
  const float* x = (const float*)d_in[0];
  const float* w1 = (const float*)d_in[1];
  const float* b1 = (const float*)d_in[2];
  const float* w2 = (const float*)d_in[3];
  const float* b2 = (const float*)d_in[4];
  float* out = (float*)d_out;
  float* means = (float*)d_ws;  // 16384 floats

  // K0: mean(chunk 0)
  se_fused<<<CHUNK_ROWS, 256, 0, stream>>>(x, w1, b1, w2, b2, out, means,
                                           /*mean_base=*/0, /*scale_base=*/-1,
                                           /*both=*/0);
  // K1..K7: mean(chunk k) + scale(chunk k-1)
  for (int k = 1; k < NCHUNK; ++k) {
    se_fused<<<2 * CHUNK_ROWS, 256, 0, stream>>>(
        x, w1, b1, w2, b2, out, means,
        /*mean_base=*/k * CHUNK_ROWS, /*scale_base=*/(k - 1) * CHUNK_ROWS,
        /*both=*/1);
  }
  // K8: scale(chunk 7)
  se_fused<<<CHUNK_ROWS, 256, 0, stream>>>(
      x, w1, b1, w2, b2, out, means,
      /*mean_base=*/-1, /*scale_base=*/(NCHUNK - 1) * CHUNK_ROWS, /*both=*/0);
}